// Round 9
// baseline (241.148 us; speedup 1.0000x reference)
//
#include <hip/hip_runtime.h>
#include <math.h>

#define NQ   12
#define NL   4
#define DIM  4096          // 2^NQ
#define BLK  256
#define APT  16            // amplitudes per thread

typedef float v2f __attribute__((ext_vector_type(2)));

// Word address of amplitude i's real part (imag at +1). Interleaved re/im,
// XOR bank swizzle f(i) = (i>>4 ^ i>>8)&7 into word bits 2..4 (keeps 16B align).
// GF(2)-linear for disjoint-bit arguments.
__device__ __forceinline__ constexpr int wmix(int i) {
    return (i << 1) ^ ((((i >> 4) ^ (i >> 8)) & 7) << 2);
}

// CNOT-ring gather map: final[i] = pre[sigma_c(i)]. GF(2)-linear.
__device__ __forceinline__ constexpr int sigma_c(int i) {
    int j = i;
    for (int c = NQ - 1; c >= 0; --c) {
        int t = (c + 1) % NQ;
        int cb = (j >> (NQ - 1 - c)) & 1;
        j ^= cb << (NQ - 1 - t);
    }
    return j;
}
// Inverse map (CNOTs are involutions; apply in forward order) — for the
// sigma-folded scatter: store pre[i] at slot sigma_inv(i).
__device__ __forceinline__ constexpr int sigma_inv_c(int i) {
    int j = i;
    for (int c = 0; c < NQ; ++c) {
        int t = (c + 1) % NQ;
        int cb = (j >> (NQ - 1 - c)) & 1;
        j ^= cb << (NQ - 1 - t);
    }
    return j;
}

// ---- VALU lane exchanges via DPP (no DS pipe) ----
// Direction convention (verified vs shfl_up/down lowering): row_shr:n = lane i
// reads lane i-n; row_shl:n = lane i reads lane i+n.
__device__ __forceinline__ float dxor1(float x) {   // quad_perm [1,0,3,2]
    return __int_as_float(__builtin_amdgcn_update_dpp(
        0, __float_as_int(x), 0xB1, 0xF, 0xF, true));
}
__device__ __forceinline__ float dxor2(float x) {   // quad_perm [2,3,0,1]
    return __int_as_float(__builtin_amdgcn_update_dpp(
        0, __float_as_int(x), 0x4E, 0xF, 0xF, true));
}
__device__ __forceinline__ float dxor8(float x) {   // row_ror:8 (rot8 of 16 = xor8)
    return __int_as_float(__builtin_amdgcn_update_dpp(
        0, __float_as_int(x), 0x128, 0xF, 0xF, true));
}
__device__ __forceinline__ float dxor4(float x) {   // 2-op: banks 1,3 read i-4; banks 0,2 read i+4
    const int xi = __float_as_int(x);
    int t = __builtin_amdgcn_update_dpp(0, xi, 0x114, 0xF, 0xA, true);  // row_shr:4 -> banks 1,3
    t = __builtin_amdgcn_update_dpp(t, xi, 0x104, 0xF, 0x5, false);     // row_shl:4 -> banks 0,2
    return __int_as_float(t);
}

// Packed-complex gate update: N0 = u00*A0 + u01*A1, N1 = u10*A0 + u11*A1.
#define CGATE(AV, R0, R1)                                            \
  { const v2f A0 = AV[R0], A1 = AV[R1];                              \
    const v2f A0s = { -A0.y, A0.x };                                 \
    const v2f A1s = { -A1.y, A1.x };                                 \
    v2f N0 = b00r * A0;                                              \
    N0 = __builtin_elementwise_fma(b00i, A0s, N0);                   \
    N0 = __builtin_elementwise_fma(b01r, A1,  N0);                   \
    N0 = __builtin_elementwise_fma(b01i, A1s, N0);                   \
    v2f N1 = b10r * A0;                                              \
    N1 = __builtin_elementwise_fma(b10i, A0s, N1);                   \
    N1 = __builtin_elementwise_fma(b11r, A1,  N1);                   \
    N1 = __builtin_elementwise_fma(b11i, A1s, N1);                   \
    AV[R0] = N0; AV[R1] = N1; }

// 4 gates on register-index bits 3..0; bit j <-> wire WB+3-j. Splat gates
// from global (wave-uniform -> SMEM path).
#define APPLY4(LB, WB)                                               \
  { _Pragma("unroll")                                                \
    for (int j = 0; j < 4; ++j) {                                    \
      const int gb = ((LB) + (WB) + 3 - j) * 8;                      \
      const v2f b00r = gg[gb + 0], b00i = gg[gb + 1];                \
      const v2f b01r = gg[gb + 2], b01i = gg[gb + 3];                \
      const v2f b10r = gg[gb + 4], b10i = gg[gb + 5];                \
      const v2f b11r = gg[gb + 6], b11i = gg[gb + 7];                \
      _Pragma("unroll")                                              \
      for (int h = 0; h < 8; ++h) {                                  \
        const int r0 = ((h >> j) << (j + 1)) | (h & ((1 << j) - 1)); \
        CGATE(av, r0, r0 | (1 << j));                                \
      }                                                              \
    } }

// One gate on a lane bit: partner via DPP exchange, per-lane coeff select.
// Lane with bit=0: N = u00*A + u01*P ; bit=1: N = u11*A + u10*P.
#define DPPGATE(GB, HIM, XF)                                         \
  { const v2f u00r = gg[(GB) + 0], u00i = gg[(GB) + 1];              \
    const v2f u01r = gg[(GB) + 2], u01i = gg[(GB) + 3];              \
    const v2f u10r = gg[(GB) + 4], u10i = gg[(GB) + 5];              \
    const v2f u11r = gg[(GB) + 6], u11i = gg[(GB) + 7];              \
    const v2f cor = (HIM) ? u11r : u00r;                             \
    const v2f coi = (HIM) ? u11i : u00i;                             \
    const v2f ctr = (HIM) ? u10r : u01r;                             \
    const v2f cti = (HIM) ? u10i : u01i;                             \
    _Pragma("unroll")                                                \
    for (int r = 0; r < APT; ++r) {                                  \
      const v2f A = av[r];                                           \
      const v2f P = { XF(A.x), XF(A.y) };                            \
      const v2f As = { -A.y, A.x };                                  \
      const v2f Ps = { -P.y, P.x };                                  \
      v2f N = cor * A;                                               \
      N = __builtin_elementwise_fma(coi, As, N);                     \
      N = __builtin_elementwise_fma(ctr, P,  N);                     \
      N = __builtin_elementwise_fma(cti, Ps, N);                     \
      av[r] = N;                                                     \
    } }

// ---- pre-kernel: fuse RZ*RY*RX into d_ws, each coeff duplicated (splat) ----
__global__ __launch_bounds__(64) void gate_kernel(
    const float* __restrict__ qw, float* __restrict__ gout)
{
    const int t = threadIdx.x;
    if (t < NL * NQ) {
        const int p = (t / NQ) * 3 * NQ + 3 * (t % NQ);
        float t1 = qw[p], t2 = qw[p + 1], t3 = qw[p + 2];
        float a, b, c, d, gr, h;
        sincosf(0.5f * t1, &b, &a);   // RX
        sincosf(0.5f * t2, &d, &c);   // RY
        sincosf(0.5f * t3, &h, &gr);  // RZ
        float m00r =  c * a, m00i =  d * b;
        float m01r = -d * a, m01i = -c * b;
        float m10r =  d * a, m10i = -c * b;
        float m11r =  c * a, m11i = -d * b;
        float G[8];
        G[0] = gr * m00r + h * m00i;  G[1] = gr * m00i - h * m00r;
        G[2] = gr * m01r + h * m01i;  G[3] = gr * m01i - h * m01r;
        G[4] = gr * m10r - h * m10i;  G[5] = gr * m10i + h * m10r;
        G[6] = gr * m11r - h * m11i;  G[7] = gr * m11i + h * m11r;
        #pragma unroll
        for (int k = 0; k < 8; ++k) {
            gout[t * 16 + 2 * k]     = G[k];
            gout[t * 16 + 2 * k + 1] = G[k];
        }
    }
}

__global__ __launch_bounds__(BLK) void qsim_kernel(
    const float* __restrict__ x,      // (B, 12)
    const float* __restrict__ gates,  // (48*16,) splat gate matrices from d_ws
    const float* __restrict__ dw,     // (12, 12)
    const float* __restrict__ db,     // (12,)
    float* __restrict__ out)          // (B, 12)
{
    __shared__ __align__(16) float sh[2 * DIM];   // 32768 B (5 blocks/CU)
    float* xv    = sh;        // aliases, dead once state staged
    float* enc_c = sh + 16;
    float* enc_s = sh + 32;
    float* red   = sh;        // reused after final barrier

    const int tid  = threadIdx.x;
    const int lane = tid & 63;
    const int wv   = tid >> 6;
    const int s    = blockIdx.x;
    const v2f* __restrict__ gg = (const v2f*)gates;

    if (tid < NQ) xv[tid] = x[s * NQ + tid];
    __syncthreads();
    if (tid < NQ) {
        float ss = 0.f;
        #pragma unroll
        for (int j = 0; j < NQ; ++j) ss += xv[j] * xv[j];
        float inv = rsqrtf(fmaxf(ss, 1e-12f));
        float mx = 0.f;
        #pragma unroll
        for (int j = 0; j < NQ; ++j) mx = fmaxf(mx, fabsf(xv[j] * inv));
        float ang = 3.14159265358979323846f * (xv[tid] * inv) / (mx + 1e-8f);
        float cc, sn;
        sincosf(0.5f * ang, &sn, &cc);
        enc_c[tid] = cc; enc_s[tid] = sn;
    }
    __syncthreads();

    // ---- product-state init in registers (O1: i = (tid<<4)|r) ----
    v2f av[APT];
    {
        float prefix = 1.f;
        #pragma unroll
        for (int w = 0; w < 8; ++w)
            prefix *= ((tid >> (7 - w)) & 1) ? enc_s[w] : enc_c[w];
        float u4[4], v4[4];
        #pragma unroll
        for (int k = 0; k < 4; ++k) {
            u4[k] = ((k & 2) ? enc_s[8]  : enc_c[8])  * ((k & 1) ? enc_s[9]  : enc_c[9]);
            v4[k] = ((k & 2) ? enc_s[10] : enc_c[10]) * ((k & 1) ? enc_s[11] : enc_c[11]);
        }
        #pragma unroll
        for (int r = 0; r < APT; ++r)
            av[r] = (v2f){ prefix * u4[r >> 2] * v4[r & 3], 0.f };
    }
    __syncthreads();   // enc reads done before W_A overwrites the alias region

    // Address bases (per-r offsets are compile-time XORs; maps GF(2)-linear).
    const int a1 = wmix(tid << 4);   // O1 region (W_A, R1')
    const int a3 = wmix(tid);        // OB: i = (r<<8)|tid  (R_B)
    int aW;                          // sigma_inv scatter base (W_Bsigma)
    {
        int j = tid;
        #pragma unroll
        for (int c = 0; c < NQ; ++c) {
            int t = (c + 1) % NQ;
            int cb = (j >> (NQ - 1 - c)) & 1;
            j ^= cb << (NQ - 1 - t);
        }
        aW = wmix(j);
    }

    const bool hi1 = (lane & 1) != 0;
    const bool hi2 = (lane & 2) != 0;
    const bool hi4 = (lane & 4) != 0;
    const bool hi8 = (lane & 8) != 0;

    // ---- layers: 8 reg/DPP gates + W_A | R_B + 4 gates + W_Bsigma | R1' ----
    #pragma unroll
    for (int l = 0; l < NL; ++l) {
        const int LB = l * NQ;

        APPLY4(LB, 8);                       // wires 8..11 on bits i3..i0
        DPPGATE((LB + 7) * 8, hi1, dxor1);   // wire 7 = lane bit 0
        DPPGATE((LB + 6) * 8, hi2, dxor2);   // wire 6 = lane bit 1
        DPPGATE((LB + 5) * 8, hi4, dxor4);   // wire 5 = lane bit 2
        DPPGATE((LB + 4) * 8, hi8, dxor8);   // wire 4 = lane bit 3

        #pragma unroll
        for (int k = 0; k < 8; ++k)          // W_A: b128 to own O1 region
            *(float4*)&sh[a1 ^ wmix(2 * k)] =
                make_float4(av[2 * k].x, av[2 * k].y, av[2 * k + 1].x, av[2 * k + 1].y);
        __syncthreads();

        #pragma unroll
        for (int r = 0; r < APT; ++r)        // R_B: own bits i11..i8
            av[r] = *(const v2f*)&sh[a3 ^ wmix(r << 8)];
        APPLY4(LB, 0);                       // wires 0..3
        #pragma unroll
        for (int r = 0; r < APT; ++r)        // W_Bsigma: scatter through sigma_inv
            *(v2f*)&sh[aW ^ wmix(sigma_inv_c(r << 8))] = av[r];
        __syncthreads();

        #pragma unroll
        for (int k = 0; k < 8; ++k) {        // R1': contiguous b128, own O1 region
            const float4 v = *(const float4*)&sh[a1 ^ wmix(2 * k)];
            av[2 * k]     = (v2f){ v.x, v.y };
            av[2 * k + 1] = (v2f){ v.z, v.w };
        }
        // no barrier: next W_A rewrites only this thread's own just-read slots
    }

    // ---- Z expectations (state in O1 ownership) ----
    float S = 0.f, a8 = 0.f, a9 = 0.f, a10 = 0.f, a11 = 0.f;
    #pragma unroll
    for (int r = 0; r < APT; ++r) {
        const float pr = av[r].x * av[r].x + av[r].y * av[r].y;
        S += pr;
        a8  += (r & 8) ? -pr : pr;
        a9  += (r & 4) ? -pr : pr;
        a10 += (r & 2) ? -pr : pr;
        a11 += (r & 1) ? -pr : pr;
    }
    float vals[NQ];
    #pragma unroll
    for (int w = 0; w < 8; ++w)
        vals[w] = ((tid >> (7 - w)) & 1) ? -S : S;
    vals[8] = a8; vals[9] = a9; vals[10] = a10; vals[11] = a11;
    #pragma unroll
    for (int m = 1; m <= 32; m <<= 1) {
        #pragma unroll
        for (int w = 0; w < NQ; ++w) vals[w] += __shfl_xor(vals[w], m);
    }
    __syncthreads();   // all waves done with sh before red alias is written
    if (lane == 0) {
        #pragma unroll
        for (int w = 0; w < NQ; ++w) red[wv * NQ + w] = vals[w];
    }
    __syncthreads();
    if (tid < NQ)
        red[48 + tid] = red[tid] + red[NQ + tid] + red[2 * NQ + tid] + red[3 * NQ + tid];
    __syncthreads();
    if (tid < NQ) {
        float v = db[tid];
        #pragma unroll
        for (int w = 0; w < NQ; ++w) v += red[48 + w] * dw[w * NQ + tid];
        out[s * NQ + tid] = tanhf(v);
    }
}

extern "C" void kernel_launch(void* const* d_in, const int* in_sizes, int n_in,
                              void* d_out, int out_size, void* d_ws, size_t ws_size,
                              hipStream_t stream) {
    const float* x  = (const float*)d_in[0];
    const float* qw = (const float*)d_in[1];
    const float* dw = (const float*)d_in[2];
    const float* db = (const float*)d_in[3];
    float* out   = (float*)d_out;
    float* gates = (float*)d_ws;            // 48*16 floats = 3072 B
    int batch = in_sizes[0] / NQ;
    gate_kernel<<<1, 64, 0, stream>>>(qw, gates);
    qsim_kernel<<<batch, BLK, 0, stream>>>(x, gates, dw, db, out);
}

// Round 10
// 178.136 us; speedup vs baseline: 1.3537x; 1.3537x over previous
//
#include <hip/hip_runtime.h>
#include <math.h>

#define NQ   12
#define NL   4
#define DIM  4096          // 2^NQ
#define BLK  256
#define APT  16            // amplitudes per thread

typedef float v2f __attribute__((ext_vector_type(2)));

// Word address of amplitude i's real part (imag at +1). Interleaved re/im,
// XOR bank swizzle f(i) = (i>>4 ^ i>>8)&7 into word bits 2..4 (keeps 16B align).
// GF(2)-linear for disjoint-bit arguments.
__device__ __forceinline__ constexpr int wmix(int i) {
    return (i << 1) ^ ((((i >> 4) ^ (i >> 8)) & 7) << 2);
}

// Inverse CNOT-ring map (CNOTs are involutions; apply in forward order) — for
// the sigma-folded scatter: store pre[i] at slot sigma_inv(i).
__device__ __forceinline__ constexpr int sigma_inv_c(int i) {
    int j = i;
    for (int c = 0; c < NQ; ++c) {
        int t = (c + 1) % NQ;
        int cb = (j >> (NQ - 1 - c)) & 1;
        j ^= cb << (NQ - 1 - t);
    }
    return j;
}

// Packed-complex gate update: N0 = u00*A0 + u01*A1, N1 = u10*A0 + u11*A1.
// Gate table stores real coeffs as {ur,ur} and imag coeffs as {-ui,+ui}, so
// the shuffled term is a PURE half-swap (no negate) -> folds to op_sel:[1,0].
//   {ur,ur}*A + {-ui,+ui}*swap(A) = (ur*Ar - ui*Ai, ur*Ai + ui*Ar) = u*A.
#define CGATE(AV, R0, R1)                                            \
  { const v2f A0 = AV[R0], A1 = AV[R1];                              \
    const v2f A0s = __builtin_shufflevector(A0, A0, 1, 0);           \
    const v2f A1s = __builtin_shufflevector(A1, A1, 1, 0);           \
    v2f N0 = b00r * A0;                                              \
    N0 = __builtin_elementwise_fma(b00i, A0s, N0);                   \
    N0 = __builtin_elementwise_fma(b01r, A1,  N0);                   \
    N0 = __builtin_elementwise_fma(b01i, A1s, N0);                   \
    v2f N1 = b10r * A0;                                              \
    N1 = __builtin_elementwise_fma(b10i, A0s, N1);                   \
    N1 = __builtin_elementwise_fma(b11r, A1,  N1);                   \
    N1 = __builtin_elementwise_fma(b11i, A1s, N1);                   \
    AV[R0] = N0; AV[R1] = N1; }

// 4 gates on register-index bits 3..0; bit j <-> wire WB+3-j. Gate coeffs are
// wave-uniform global loads (scalar path).
#define APPLY4(LB, WB)                                               \
  { _Pragma("unroll")                                                \
    for (int j = 0; j < 4; ++j) {                                    \
      const int gb = ((LB) + (WB) + 3 - j) * 8;                      \
      const v2f b00r = gg[gb + 0], b00i = gg[gb + 1];                \
      const v2f b01r = gg[gb + 2], b01i = gg[gb + 3];                \
      const v2f b10r = gg[gb + 4], b10i = gg[gb + 5];                \
      const v2f b11r = gg[gb + 6], b11i = gg[gb + 7];                \
      _Pragma("unroll")                                              \
      for (int h = 0; h < 8; ++h) {                                  \
        const int r0 = ((h >> j) << (j + 1)) | (h & ((1 << j) - 1)); \
        CGATE(av, r0, r0 | (1 << j));                                \
      }                                                              \
    } }

// ---- pre-kernel: fuse RZ*RY*RX into d_ws ----
// Per gate 16 floats: entry k (u00,u01,u10,u11): [4k]={ur,ur}, [4k+2]={-ui,+ui}.
__global__ __launch_bounds__(64) void gate_kernel(
    const float* __restrict__ qw, float* __restrict__ gout)
{
    const int t = threadIdx.x;
    if (t < NL * NQ) {
        const int p = (t / NQ) * 3 * NQ + 3 * (t % NQ);
        float t1 = qw[p], t2 = qw[p + 1], t3 = qw[p + 2];
        float a, b, c, d, gr, h;
        sincosf(0.5f * t1, &b, &a);   // RX
        sincosf(0.5f * t2, &d, &c);   // RY
        sincosf(0.5f * t3, &h, &gr);  // RZ
        float m00r =  c * a, m00i =  d * b;
        float m01r = -d * a, m01i = -c * b;
        float m10r =  d * a, m10i = -c * b;
        float m11r =  c * a, m11i = -d * b;
        float G[8];
        G[0] = gr * m00r + h * m00i;  G[1] = gr * m00i - h * m00r;
        G[2] = gr * m01r + h * m01i;  G[3] = gr * m01i - h * m01r;
        G[4] = gr * m10r - h * m10i;  G[5] = gr * m10i + h * m10r;
        G[6] = gr * m11r - h * m11i;  G[7] = gr * m11i + h * m11r;
        #pragma unroll
        for (int k = 0; k < 4; ++k) {
            gout[t * 16 + 4 * k + 0] =  G[2 * k];
            gout[t * 16 + 4 * k + 1] =  G[2 * k];
            gout[t * 16 + 4 * k + 2] = -G[2 * k + 1];
            gout[t * 16 + 4 * k + 3] =  G[2 * k + 1];
        }
    }
}

__global__ __launch_bounds__(BLK) void qsim_kernel(
    const float* __restrict__ x,      // (B, 12)
    const float* __restrict__ gates,  // (48*16,) arranged gate matrices (d_ws)
    const float* __restrict__ dw,     // (12, 12)
    const float* __restrict__ db,     // (12,)
    float* __restrict__ out)          // (B, 12)
{
    __shared__ __align__(16) float sh[2 * DIM];   // 32768 B (5 blocks/CU)
    float* xv    = sh;        // aliases, dead once state staged
    float* enc_c = sh + 16;
    float* enc_s = sh + 32;
    float* red   = sh;        // reused after final barrier

    const int tid  = threadIdx.x;
    const int lane = tid & 63;
    const int wv   = tid >> 6;
    const int s    = blockIdx.x;
    const v2f* __restrict__ gg = (const v2f*)gates;

    if (tid < NQ) xv[tid] = x[s * NQ + tid];
    __syncthreads();
    if (tid < NQ) {
        float ss = 0.f;
        #pragma unroll
        for (int j = 0; j < NQ; ++j) ss += xv[j] * xv[j];
        float inv = rsqrtf(fmaxf(ss, 1e-12f));
        float mx = 0.f;
        #pragma unroll
        for (int j = 0; j < NQ; ++j) mx = fmaxf(mx, fabsf(xv[j] * inv));
        float ang = 3.14159265358979323846f * (xv[tid] * inv) / (mx + 1e-8f);
        float cc, sn;
        sincosf(0.5f * ang, &sn, &cc);
        enc_c[tid] = cc; enc_s[tid] = sn;
    }
    __syncthreads();

    // ---- product-state init in registers (O1: i = (tid<<4)|r) ----
    v2f av[APT];
    {
        float prefix = 1.f;
        #pragma unroll
        for (int w = 0; w < 8; ++w)
            prefix *= ((tid >> (7 - w)) & 1) ? enc_s[w] : enc_c[w];
        float u4[4], v4[4];
        #pragma unroll
        for (int k = 0; k < 4; ++k) {
            u4[k] = ((k & 2) ? enc_s[8]  : enc_c[8])  * ((k & 1) ? enc_s[9]  : enc_c[9]);
            v4[k] = ((k & 2) ? enc_s[10] : enc_c[10]) * ((k & 1) ? enc_s[11] : enc_c[11]);
        }
        #pragma unroll
        for (int r = 0; r < APT; ++r)
            av[r] = (v2f){ prefix * u4[r >> 2] * v4[r & 3], 0.f };
    }
    __syncthreads();   // enc reads done before W1 overwrites the alias region

    // Address bases (per-r offsets are compile-time XORs; maps GF(2)-linear).
    const int a1 = wmix(tid << 4);                           // O1 (W1, R1')
    const int a2 = wmix(((tid & 0xF0) << 4) | (tid & 0x0F)); // O2: i=th<<8|r<<4|tl
    const int a3 = wmix(tid);                                // O3: i=(r<<8)|tid
    int aW;                                                  // sigma_inv scatter base
    {
        int j = tid;
        #pragma unroll
        for (int c = 0; c < NQ; ++c) {
            int t = (c + 1) % NQ;
            int cb = (j >> (NQ - 1 - c)) & 1;
            j ^= cb << (NQ - 1 - t);
        }
        aW = wmix(j);
    }

    // ---- layers: 12 register gates, 3 LDS round trips, 3 barriers each ----
    // Rolled (not unrolled): body ~4x smaller, fits I$ with 4x reuse.
    #pragma unroll 1
    for (int l = 0; l < NL; ++l) {
        const int LB = l * NQ;

        APPLY4(LB, 8);                       // wires 8..11 on bits i3..i0
        #pragma unroll
        for (int k = 0; k < 8; ++k)          // W1: b128 to own O1 region
            *(float4*)&sh[a1 ^ wmix(2 * k)] =
                make_float4(av[2 * k].x, av[2 * k].y, av[2 * k + 1].x, av[2 * k + 1].y);
        __syncthreads();

        #pragma unroll
        for (int r = 0; r < APT; ++r)        // R2: own bits i7..i4
            av[r] = *(const v2f*)&sh[a2 ^ wmix(r << 4)];
        APPLY4(LB, 4);                       // wires 4..7
        #pragma unroll
        for (int r = 0; r < APT; ++r)        // W2: same addresses as R2
            *(v2f*)&sh[a2 ^ wmix(r << 4)] = av[r];
        __syncthreads();

        #pragma unroll
        for (int r = 0; r < APT; ++r)        // R3: own bits i11..i8
            av[r] = *(const v2f*)&sh[a3 ^ wmix(r << 8)];
        APPLY4(LB, 0);                       // wires 0..3
        #pragma unroll
        for (int r = 0; r < APT; ++r)        // W3σ: scatter through sigma_inv
            *(v2f*)&sh[aW ^ wmix(sigma_inv_c(r << 8))] = av[r];
        __syncthreads();

        #pragma unroll
        for (int k = 0; k < 8; ++k) {        // R1': contiguous b128, own O1 region
            const float4 v = *(const float4*)&sh[a1 ^ wmix(2 * k)];
            av[2 * k]     = (v2f){ v.x, v.y };
            av[2 * k + 1] = (v2f){ v.z, v.w };
        }
        // no barrier: next W1 rewrites only this thread's own just-read slots
    }

    // ---- Z expectations (state in O1 ownership) ----
    float S = 0.f, a8 = 0.f, a9 = 0.f, a10 = 0.f, a11 = 0.f;
    #pragma unroll
    for (int r = 0; r < APT; ++r) {
        const float pr = av[r].x * av[r].x + av[r].y * av[r].y;
        S += pr;
        a8  += (r & 8) ? -pr : pr;
        a9  += (r & 4) ? -pr : pr;
        a10 += (r & 2) ? -pr : pr;
        a11 += (r & 1) ? -pr : pr;
    }
    float vals[NQ];
    #pragma unroll
    for (int w = 0; w < 8; ++w)
        vals[w] = ((tid >> (7 - w)) & 1) ? -S : S;
    vals[8] = a8; vals[9] = a9; vals[10] = a10; vals[11] = a11;
    #pragma unroll
    for (int m = 1; m <= 32; m <<= 1) {
        #pragma unroll
        for (int w = 0; w < NQ; ++w) vals[w] += __shfl_xor(vals[w], m);
    }
    __syncthreads();   // all waves done with sh before red alias is written
    if (lane == 0) {
        #pragma unroll
        for (int w = 0; w < NQ; ++w) red[wv * NQ + w] = vals[w];
    }
    __syncthreads();
    if (tid < NQ)
        red[48 + tid] = red[tid] + red[NQ + tid] + red[2 * NQ + tid] + red[3 * NQ + tid];
    __syncthreads();
    if (tid < NQ) {
        float v = db[tid];
        #pragma unroll
        for (int w = 0; w < NQ; ++w) v += red[48 + w] * dw[w * NQ + tid];
        out[s * NQ + tid] = tanhf(v);
    }
}

extern "C" void kernel_launch(void* const* d_in, const int* in_sizes, int n_in,
                              void* d_out, int out_size, void* d_ws, size_t ws_size,
                              hipStream_t stream) {
    const float* x  = (const float*)d_in[0];
    const float* qw = (const float*)d_in[1];
    const float* dw = (const float*)d_in[2];
    const float* db = (const float*)d_in[3];
    float* out   = (float*)d_out;
    float* gates = (float*)d_ws;            // 48*16 floats = 3072 B
    int batch = in_sizes[0] / NQ;
    gate_kernel<<<1, 64, 0, stream>>>(qw, gates);
    qsim_kernel<<<batch, BLK, 0, stream>>>(x, gates, dw, db, out);
}